// Round 14
// baseline (73.319 us; speedup 1.0000x reference)
//
#include <hip/hip_runtime.h>

#define BATCH   8
#define HW      (1024 * 1024)
#define NA      512
#define EPSV    1e-8f
#define LAML    0.01f
#define LAMS    0.01f

#define BPB      128                        // blocks per batch
#define NBLOCKS  (BATCH * BPB)              // 1024 = 4 blocks/CU
#define PIXB     (HW / BPB)                 // 8192 pixels per block
#define UNROLL   8                          // float4 groups per thread (32 px)

#define NCOPY    16                         // privatized bin columns (32 KB LDS)
#define SCALE    4194304.0f                 // 2^22 fixed-point scale
#define INVSCALE (1.0f / 4194304.0f)
// packed word: (admin_id << 23) | q22(score);  score < 1.0201 -> q22 < 2^23

#define PAD      64                         // u32 words: 256 B per batch slot

typedef unsigned long long u64;
typedef float vf4 __attribute__((ext_vector_type(4)));   // nt-store-compatible

// Pass 1: LDS u32 histogram + pck pack; flush via u64 atomics to gsum;
// the LAST block of each batch (detected by arrival counter) computes the
// factor table. No spin, no grid barrier — stream ordering does the rest.
__global__ __launch_bounds__(256, 4)
void k_sums(const float* __restrict__ lights,
            const float* __restrict__ settle,
            const int*   __restrict__ admin,
            const float* __restrict__ census,
            u64*         __restrict__ gsum,      // BATCH*NA u64, zeroed
            unsigned*    __restrict__ ctr,       // BATCH*PAD u32, zeroed
            float*       __restrict__ factor,    // BATCH*NA f32
            unsigned*    __restrict__ pck) {
    __shared__ unsigned int bins[NA * NCOPY];    // 32 KB
    __shared__ unsigned int last;
    const int tid = threadIdx.x;
    const int b   = blockIdx.x >> 7;             // / BPB

    #pragma unroll
    for (int i = tid; i < NA * NCOPY; i += 256) bins[i] = 0u;
    __syncthreads();

    const long base = (long)blockIdx.x * PIXB;
    const float4* __restrict__ L4 = (const float4*)(lights + base);
    const float4* __restrict__ S4 = (const float4*)(settle + base);
    const int4*   __restrict__ A4 = (const int4*)(admin + base);
    uint4*        __restrict__ P4 = (uint4*)(pck + base);

    float4 l[UNROLL], s[UNROLL];
    int4   a[UNROLL];
    #pragma unroll
    for (int u = 0; u < UNROLL; ++u) {
        const int v = tid + u * 256;
        l[u] = L4[v];
        s[u] = S4[v];
        a[u] = A4[v];
    }
    __builtin_amdgcn_sched_barrier(0);           // keep all 24 loads in flight

    const int c = tid & (NCOPY - 1);
    #pragma unroll
    for (int u = 0; u < UNROLL; ++u) {
        const unsigned qx = (unsigned)((l[u].x + LAML) * (s[u].x + LAMS) * SCALE + 0.5f);
        const unsigned qy = (unsigned)((l[u].y + LAML) * (s[u].y + LAMS) * SCALE + 0.5f);
        const unsigned qz = (unsigned)((l[u].z + LAML) * (s[u].z + LAMS) * SCALE + 0.5f);
        const unsigned qw = (unsigned)((l[u].w + LAML) * (s[u].w + LAMS) * SCALE + 0.5f);
        uint4 pk;
        pk.x = ((unsigned)a[u].x << 23) | qx;
        pk.y = ((unsigned)a[u].y << 23) | qy;
        pk.z = ((unsigned)a[u].z << 23) | qz;
        pk.w = ((unsigned)a[u].w << 23) | qw;
        P4[tid + u * 256] = pk;                  // fire-and-forget store
        atomicAdd(&bins[a[u].x * NCOPY + c], qx);
        atomicAdd(&bins[a[u].y * NCOPY + c], qy);
        atomicAdd(&bins[a[u].z * NCOPY + c], qz);
        atomicAdd(&bins[a[u].w * NCOPY + c], qw);
    }
    __syncthreads();

    // flush block totals: coalesced u64 integer atomics (native, cheap)
    for (int i = tid; i < NA; i += 256) {
        u64 t = 0;
        #pragma unroll
        for (int k = 0; k < NCOPY; ++k) t += bins[i * NCOPY + k];
        atomicAdd(&gsum[b * NA + i], t);
    }
    __syncthreads();

    // arrival count; the last block of this batch computes the factor table
    if (tid == 0) {
        unsigned prev = __hip_atomic_fetch_add(&ctr[b * PAD], 1u,
                                               __ATOMIC_ACQ_REL,
                                               __HIP_MEMORY_SCOPE_AGENT);
        last = (prev == (unsigned)(BPB - 1)) ? 1u : 0u;
    }
    __syncthreads();
    if (last) {
        for (int i = tid; i < NA; i += 256) {
            u64 t = __hip_atomic_load(&gsum[b * NA + i], __ATOMIC_RELAXED,
                                      __HIP_MEMORY_SCOPE_AGENT);
            factor[b * NA + i] = census[i] / ((float)t * INVSCALE + EPSV);
        }
    }
}

// Pass 2: read packed (admin,score), gather factor from LDS, nt-store out.
__global__ __launch_bounds__(256, 4) void k_out(const unsigned* __restrict__ pck,
                                                const float*    __restrict__ factor,
                                                float*          __restrict__ out) {
    __shared__ float lfac[NA];
    const int tid = threadIdx.x;
    const int b   = blockIdx.x >> 7;             // / BPB

    for (int i = tid; i < NA; i += 256)
        lfac[i] = factor[b * NA + i];
    __syncthreads();

    const long base = (long)blockIdx.x * PIXB;
    const uint4* __restrict__ P4 = (const uint4*)(pck + base);
    vf4*         __restrict__ O4 = (vf4*)(out + base);

    uint4 p[UNROLL];
    #pragma unroll
    for (int u = 0; u < UNROLL; ++u) p[u] = P4[tid + u * 256];
    __builtin_amdgcn_sched_barrier(0);           // 8 loads in flight

    #pragma unroll
    for (int u = 0; u < UNROLL; ++u) {
        vf4 o;
        o.x = (float)(p[u].x & 0x7FFFFFu) * INVSCALE * lfac[p[u].x >> 23];
        o.y = (float)(p[u].y & 0x7FFFFFu) * INVSCALE * lfac[p[u].y >> 23];
        o.z = (float)(p[u].z & 0x7FFFFFu) * INVSCALE * lfac[p[u].z >> 23];
        o.w = (float)(p[u].w & 0x7FFFFFu) * INVSCALE * lfac[p[u].w >> 23];
        __builtin_nontemporal_store(o, &O4[tid + u * 256]);  // write-only stream
    }
}

extern "C" void kernel_launch(void* const* d_in, const int* in_sizes, int n_in,
                              void* d_out, int out_size, void* d_ws, size_t ws_size,
                              hipStream_t stream) {
    const float* lights = (const float*)d_in[0];
    const float* settle = (const float*)d_in[1];
    const int*   admin  = (const int*)d_in[2];
    const float* census = (const float*)d_in[3];
    float*       out    = (float*)d_out;

    u64*      gsum   = (u64*)d_ws;                                   // 32 KB
    unsigned* ctr    = (unsigned*)((char*)d_ws + BATCH * NA * sizeof(u64));
    float*    factor = (float*)(ctr + BATCH * PAD);                  // 16 KB
    unsigned* pck    = (unsigned*)d_out;         // d_out doubles as packed scratch

    // zero gsum + ctr every call (ws poisoned once, never re-poisoned)
    (void)hipMemsetAsync(d_ws, 0,
                         BATCH * NA * sizeof(u64) + BATCH * PAD * sizeof(unsigned),
                         stream);

    k_sums<<<NBLOCKS, 256, 0, stream>>>(lights, settle, admin, census,
                                        gsum, ctr, factor, pck);
    k_out <<<NBLOCKS, 256, 0, stream>>>(pck, factor, out);
}

// Round 15
// 42.068 us; speedup vs baseline: 1.7429x; 1.7429x over previous
//
#include <hip/hip_runtime.h>

#define BATCH   8
#define HW      (1024 * 1024)
#define NA      512
#define EPSV    1e-8f
#define LAML    0.01f
#define LAMS    0.01f

#define BPB      128                        // blocks per batch
#define NBLOCKS  (BATCH * BPB)              // 1024 = 4 blocks/CU
#define PIXB     (HW / BPB)                 // 8192 pixels per block
#define UNROLL   8                          // float4 groups per thread (32 px)

#define NCOPY    16                         // privatized copies, copy = tid&15
#define SCALE    4194304.0f                 // 2^22 fixed-point scale
#define INVSCALE (1.0f / 4194304.0f)
// packed word: (admin_id << 23) | q22(score);  score < 1.0201 -> q22 < 2^23

typedef float vf4 __attribute__((ext_vector_type(4)));   // nt-store-compatible

// Pass 1: u32 fixed-point LDS atomics (bins[c][a] layout: bank = a&31,
// ~2 lanes/bank at random ids = conflict-free) + pack (admin,score) into pck.
__global__ __launch_bounds__(256, 4) void k_sums(const float* __restrict__ lights,
                                                 const float* __restrict__ settle,
                                                 const int*   __restrict__ admin,
                                                 float*       __restrict__ partial,
                                                 unsigned*    __restrict__ pck) {
    __shared__ unsigned int bins[NCOPY * NA];   // 32 KB, [copy][admin]
    const int tid = threadIdx.x;

    #pragma unroll
    for (int i = tid; i < NCOPY * NA; i += 256) bins[i] = 0u;
    __syncthreads();

    const long base = (long)blockIdx.x * PIXB;

    const float4* __restrict__ L4 = (const float4*)(lights + base);
    const float4* __restrict__ S4 = (const float4*)(settle + base);
    const int4*   __restrict__ A4 = (const int4*)(admin + base);
    uint4*        __restrict__ P4 = (uint4*)(pck + base);

    float4 l[UNROLL], s[UNROLL];
    int4   a[UNROLL];
    #pragma unroll
    for (int u = 0; u < UNROLL; ++u) {
        const int v = tid + u * 256;
        l[u] = L4[v];
        s[u] = S4[v];
        a[u] = A4[v];
    }
    __builtin_amdgcn_sched_barrier(0);          // keep all 24 loads in flight

    unsigned* bc = bins + (tid & (NCOPY - 1)) * NA;   // this thread's copy row
    #pragma unroll
    for (int u = 0; u < UNROLL; ++u) {
        const unsigned qx = (unsigned)((l[u].x + LAML) * (s[u].x + LAMS) * SCALE + 0.5f);
        const unsigned qy = (unsigned)((l[u].y + LAML) * (s[u].y + LAMS) * SCALE + 0.5f);
        const unsigned qz = (unsigned)((l[u].z + LAML) * (s[u].z + LAMS) * SCALE + 0.5f);
        const unsigned qw = (unsigned)((l[u].w + LAML) * (s[u].w + LAMS) * SCALE + 0.5f);
        uint4 pk;
        pk.x = ((unsigned)a[u].x << 23) | qx;
        pk.y = ((unsigned)a[u].y << 23) | qy;
        pk.z = ((unsigned)a[u].z << 23) | qz;
        pk.w = ((unsigned)a[u].w << 23) | qw;
        P4[tid + u * 256] = pk;                 // fire-and-forget store
        atomicAdd(&bc[a[u].x], qx);
        atomicAdd(&bc[a[u].y], qy);
        atomicAdd(&bc[a[u].z], qz);
        atomicAdd(&bc[a[u].w], qw);
    }
    __syncthreads();

    // flush block totals: plain stores, zero contention
    float* dst = partial + (long)blockIdx.x * NA;
    for (int i = tid; i < NA; i += 256) {
        unsigned long long t = 0;
        #pragma unroll
        for (int k = 0; k < NCOPY; ++k) t += bins[k * NA + i];
        dst[i] = (float)t * INVSCALE;
    }
}

// Reduce 128 chunk-partials per (batch, admin) -> factor = C/(S+eps).
// 64 blocks: (batch, 64-admin slice); 256 thr = 64 admins x 4 chunk-groups.
__global__ __launch_bounds__(256) void k_reduce(const float* __restrict__ partial,
                                                const float* __restrict__ census,
                                                float*       __restrict__ factor) {
    __shared__ float red[256];
    const int b     = blockIdx.x >> 3;
    const int slice = blockIdx.x & 7;
    const int lane  = threadIdx.x & 63;
    const int g     = threadIdx.x >> 6;
    const int a     = slice * 64 + lane;

    const float* p = partial + (long)b * BPB * NA + a;
    float acc = 0.0f;
    #pragma unroll 8
    for (int cc = g * 32; cc < g * 32 + 32; ++cc) acc += p[(long)cc * NA];
    red[threadIdx.x] = acc;
    __syncthreads();
    if (threadIdx.x < 128) red[threadIdx.x] += red[threadIdx.x + 128];
    __syncthreads();
    if (threadIdx.x < 64) {
        float t = red[threadIdx.x] + red[threadIdx.x + 64];
        factor[b * NA + a] = census[a] / (t + EPSV);
    }
}

// Pass 2: read packed (admin,score), gather factor from LDS, nt-store out.
__global__ __launch_bounds__(256, 4) void k_out(const unsigned* __restrict__ pck,
                                                const float*    __restrict__ factor,
                                                float*          __restrict__ out) {
    __shared__ float lfac[NA];
    const int tid = threadIdx.x;
    const int b   = blockIdx.x >> 7;            // / BPB

    for (int i = tid; i < NA; i += 256)
        lfac[i] = factor[b * NA + i];
    __syncthreads();

    const long base = (long)blockIdx.x * PIXB;
    const uint4* __restrict__ P4 = (const uint4*)(pck + base);
    vf4*         __restrict__ O4 = (vf4*)(out + base);

    uint4 p[UNROLL];
    #pragma unroll
    for (int u = 0; u < UNROLL; ++u) p[u] = P4[tid + u * 256];
    __builtin_amdgcn_sched_barrier(0);          // 8 loads in flight

    #pragma unroll
    for (int u = 0; u < UNROLL; ++u) {
        vf4 o;
        o.x = (float)(p[u].x & 0x7FFFFFu) * INVSCALE * lfac[p[u].x >> 23];
        o.y = (float)(p[u].y & 0x7FFFFFu) * INVSCALE * lfac[p[u].y >> 23];
        o.z = (float)(p[u].z & 0x7FFFFFu) * INVSCALE * lfac[p[u].z >> 23];
        o.w = (float)(p[u].w & 0x7FFFFFu) * INVSCALE * lfac[p[u].w >> 23];
        __builtin_nontemporal_store(o, &O4[tid + u * 256]);  // write-only stream
    }
}

extern "C" void kernel_launch(void* const* d_in, const int* in_sizes, int n_in,
                              void* d_out, int out_size, void* d_ws, size_t ws_size,
                              hipStream_t stream) {
    const float* lights = (const float*)d_in[0];
    const float* settle = (const float*)d_in[1];
    const int*   admin  = (const int*)d_in[2];
    const float* census = (const float*)d_in[3];
    float*       out    = (float*)d_out;

    float* partial = (float*)d_ws;                        // NBLOCKS*NA = 2 MB
    float* factor  = (float*)d_ws + (long)NBLOCKS * NA;   // BATCH*NA
    unsigned* pck  = (unsigned*)d_out;                    // d_out doubles as packed scratch

    k_sums  <<<NBLOCKS, 256, 0, stream>>>(lights, settle, admin, partial, pck);
    k_reduce<<<64,      256, 0, stream>>>(partial, census, factor);
    k_out   <<<NBLOCKS, 256, 0, stream>>>(pck, factor, out);
}